// Round 1
// baseline (88.419 us; speedup 1.0000x reference)
//
#include <hip/hip_runtime.h>
#include <math.h>

#define H_DIM 512
#define N_DIM 32
#define L_LEN 1024
#define LF_LEN 513   // L/2 + 1

struct c32 { float x, y; };

__device__ __forceinline__ c32 cmul(c32 a, c32 b) {
    return { a.x*b.x - a.y*b.y, a.x*b.y + a.y*b.x };
}
__device__ __forceinline__ c32 conjc(c32 a) { return { a.x, -a.y }; }
__device__ __forceinline__ c32 crecip(c32 d) {
    float s = 1.0f / (d.x*d.x + d.y*d.y);
    return { d.x*s, -d.y*s };
}

__launch_bounds__(256)
__global__ void ssk_nplr_kernel(const float* __restrict__ log_dt,
                                const float* __restrict__ inv_w_real,
                                const float* __restrict__ w_imag,
                                const float* __restrict__ B_ri,
                                const float* __restrict__ C_ri,
                                const float* __restrict__ P_ri,
                                float* __restrict__ out)
{
    __shared__ float2 Ksh[LF_LEN];        // k_f per frequency
    __shared__ float2 s_wdt[N_DIM];       // w * dt (per-h)
    __shared__ float2 s_v00[N_DIM];       // B*C
    __shared__ float2 s_v01[N_DIM];       // B*conj(P)
    __shared__ float2 s_v10[N_DIM];       // P*C
    __shared__ float2 s_v11[N_DIM];       // P*conj(P)

    const int h   = blockIdx.x;
    const int tid = threadIdx.x;
    const float dt = expf(log_dt[h]);

    // ---------------- Phase A: per-h pole data ----------------
    if (tid < N_DIM) {
        const int n = tid;
        float wr = -expf(inv_w_real[n]);      // S=1
        float wi = w_imag[n];
        s_wdt[n] = make_float2(wr * dt, wi * dt);
        c32 B { B_ri[2*n],              B_ri[2*n + 1] };            // (1,1,N,2)
        c32 C { C_ri[h*2*N_DIM + 2*n],  C_ri[h*2*N_DIM + 2*n + 1] };// (1,H,N,2)
        c32 P { P_ri[2*n],              P_ri[2*n + 1] };            // (1,1,N,2)
        c32 Q = conjc(P);
        c32 t00 = cmul(B, C);  s_v00[n] = make_float2(t00.x, t00.y);
        c32 t01 = cmul(B, Q);  s_v01[n] = make_float2(t01.x, t01.y);
        c32 t10 = cmul(P, C);  s_v10[n] = make_float2(t10.x, t10.y);
        c32 t11 = cmul(P, Q);  s_v11[n] = make_float2(t11.x, t11.y);
    }
    __syncthreads();

    // ---------------- Phase B: k_f[j] for j in [0, 513) ----------------
    for (int j = tid; j < LF_LEN; j += 256) {
        // omega = exp(-2i*pi*j/L), computed like the reference (f32 angle)
        float ang = (-6.2831854820251465f * (float)j) * (1.0f / 1024.0f);
        float si, co;
        __sincosf(ang, &si, &co);
        // use accurate versions to stay close to numpy
        si = sinf(ang); co = cosf(ang);

        c32 onep { 1.0f + co,  si };          // 1 + omega
        c32 onem { 1.0f - co, -si };          // 1 - omega
        c32 invp = crecip(onep);
        c32 z    = cmul({ 2.0f*onem.x, 2.0f*onem.y }, invp);   // 2(1-w)/(1+w)

        c32 S00{0,0}, S01{0,0}, S10{0,0}, S11{0,0};
        #pragma unroll 8
        for (int n = 0; n < N_DIM; ++n) {
            float2 wd = s_wdt[n];
            c32 d1 { z.x - wd.x, z.y - wd.y };      // z - w*dt
            c32 d2 { z.x - wd.x, z.y + wd.y };      // z - conj(w*dt)
            c32 r1 = crecip(d1);
            c32 r2 = crecip(d2);

            float2 a;
            a = s_v00[n]; { c32 v{a.x,a.y};
                c32 p = cmul(v, r1), q = cmul(conjc(v), r2);
                S00.x += p.x + q.x; S00.y += p.y + q.y; }
            a = s_v01[n]; { c32 v{a.x,a.y};
                c32 p = cmul(v, r1), q = cmul(conjc(v), r2);
                S01.x += p.x + q.x; S01.y += p.y + q.y; }
            a = s_v10[n]; { c32 v{a.x,a.y};
                c32 p = cmul(v, r1), q = cmul(conjc(v), r2);
                S10.x += p.x + q.x; S10.y += p.y + q.y; }
            a = s_v11[n]; { c32 v{a.x,a.y};
                c32 p = cmul(v, r1), q = cmul(conjc(v), r2);
                S11.x += p.x + q.x; S11.y += p.y + q.y; }
        }
        // r = dt * S
        S00 = { S00.x*dt, S00.y*dt };
        S01 = { S01.x*dt, S01.y*dt };
        S10 = { S10.x*dt, S10.y*dt };
        S11 = { S11.x*dt, S11.y*dt };

        // k_f = r00 - r01 * r10 / (1 + r11)
        c32 den { 1.0f + S11.x, S11.y };
        c32 corr = cmul(cmul(S01, S10), crecip(den));
        c32 kf { S00.x - corr.x, S00.y - corr.y };
        // * 2/(1+omega)
        kf = cmul(kf, { 2.0f*invp.x, 2.0f*invp.y });

        Ksh[j] = make_float2(kf.x, kf.y);
    }
    __syncthreads();

    // ---------------- Phase C: irfft (naive Hermitian DFT) ----------------
    // k[t] = (1/L) * [ K0.re + (-1)^t K512.re
    //                  + 2*sum_{j=1}^{511} (Kj.re cos(2pi j t/L) - Kj.im sin(2pi j t/L)) ]
    // 4 outputs per thread, processed together sharing the Ksh[j] read.
    {
        float2 k0  = Ksh[0];
        float2 kN  = Ksh[512];

        float accs[4];
        c32   ph[4], rot[4];
        int   ts[4];
        #pragma unroll
        for (int c = 0; c < 4; ++c) {
            int t = tid + 256*c;
            ts[c] = t;
            double sa = (double)t * (6.283185307179586 / 1024.0);
            rot[c] = { (float)cos(sa), (float)sin(sa) };   // e^{i 2pi t / L}
            ph[c]  = rot[c];                                // phase at j=1
            float sign = (t & 1) ? -1.0f : 1.0f;
            accs[c] = 0.5f*k0.x + 0.5f*sign*kN.x;
        }

        for (int j = 1; j < 512; ++j) {
            float2 kj = Ksh[j];
            #pragma unroll
            for (int c = 0; c < 4; ++c) {
                accs[c] += kj.x*ph[c].x - kj.y*ph[c].y;
                ph[c] = cmul(ph[c], rot[c]);
            }
        }

        #pragma unroll
        for (int c = 0; c < 4; ++c) {
            out[h*L_LEN + ts[c]] = accs[c] * (2.0f / 1024.0f);
        }
    }
}

extern "C" void kernel_launch(void* const* d_in, const int* in_sizes, int n_in,
                              void* d_out, int out_size, void* d_ws, size_t ws_size,
                              hipStream_t stream) {
    const float* log_dt     = (const float*)d_in[0];
    const float* inv_w_real = (const float*)d_in[1];
    const float* w_imag     = (const float*)d_in[2];
    const float* B_ri       = (const float*)d_in[3];
    const float* C_ri       = (const float*)d_in[4];
    const float* P_ri       = (const float*)d_in[5];
    // d_in[6] = L (constant 1024, baked in)

    ssk_nplr_kernel<<<H_DIM, 256, 0, stream>>>(log_dt, inv_w_real, w_imag,
                                               B_ri, C_ri, P_ri, (float*)d_out);
}

// Round 2
// 23.837 us; speedup vs baseline: 3.7093x; 3.7093x over previous
//
#include <hip/hip_runtime.h>
#include <math.h>

#define H_DIM 512
#define N_DIM 32
#define L_LEN 1024
#define LF_LEN 513   // L/2 + 1
#define M_FFT 512    // L/2

struct c32 { float x, y; };

__device__ __forceinline__ c32 cmul(c32 a, c32 b) {
    return { a.x*b.x - a.y*b.y, a.x*b.y + a.y*b.x };
}
__device__ __forceinline__ c32 crecip(c32 d) {
    float s = 1.0f / (d.x*d.x + d.y*d.y);
    return { d.x*s, -d.y*s };
}

__launch_bounds__(512)
__global__ void ssk_nplr_kernel(const float* __restrict__ log_dt,
                                const float* __restrict__ inv_w_real,
                                const float* __restrict__ w_imag,
                                const float* __restrict__ B_ri,
                                const float* __restrict__ C_ri,
                                const float* __restrict__ P_ri,
                                float* __restrict__ out)
{
    // ---- LDS ----
    __shared__ float2 Ksh[LF_LEN];                 // k_f spectrum
    __shared__ float4 polA[N_DIM];                 // {m2wr, |wdt|^2, a00, b00}
    __shared__ float4 polB[N_DIM];                 // {a01, b01, a10, b10}
    __shared__ float4 polC[N_DIM];                 // {a11, b11, 0, 0}
    __shared__ float  twr[M_FFT/2], twi[M_FFT/2];  // e^{+2pi i q/512}
    __shared__ float  Are[M_FFT], Aim[M_FFT];      // FFT ping
    __shared__ float  Bre[M_FFT], Bim[M_FFT];      // FFT pong

    const int h   = blockIdx.x;
    const int tid = threadIdx.x;
    const float dt = expf(log_dt[h]);

    // ---------------- Phase A: per-h pole data + twiddles ----------------
    if (tid < N_DIM) {
        const int n = tid;
        float wr = -expf(inv_w_real[n]);   // S=1
        float wi = w_imag[n];
        float wdx = wr * dt, wdy = wi * dt;
        c32 B { B_ri[2*n],                 B_ri[2*n + 1] };
        c32 C { C_ri[h*2*N_DIM + 2*n],     C_ri[h*2*N_DIM + 2*n + 1] };
        c32 P { P_ri[2*n],                 P_ri[2*n + 1] };
        c32 Pc { P.x, -P.y };
        c32 v00 = cmul(B, C);
        c32 v01 = cmul(B, Pc);
        c32 v10 = cmul(P, C);
        c32 v11 { P.x*P.x + P.y*P.y, 0.0f };
        polA[n] = make_float4(-2.0f*wdx, wdx*wdx + wdy*wdy,
                              2.0f*v00.x, 2.0f*(v00.x*wdx + v00.y*wdy));
        polB[n] = make_float4(2.0f*v01.x, 2.0f*(v01.x*wdx + v01.y*wdy),
                              2.0f*v10.x, 2.0f*(v10.x*wdx + v10.y*wdy));
        polC[n] = make_float4(2.0f*v11.x, 2.0f*(v11.x*wdx + v11.y*wdy), 0.0f, 0.0f);
    }
    if (tid < M_FFT/2) {
        float ang = 6.2831854820251465f * (float)tid * (1.0f/512.0f);
        twr[tid] = cosf(ang);
        twi[tid] = sinf(ang);
    }
    __syncthreads();

    // ---------------- Phase B: k_f[j] ----------------
    // j = tid for all 512 threads; thread 0 also does j = 512.
    for (int rep = 0; rep < 2; ++rep) {
        int j;
        if (rep == 0) j = tid;
        else { if (tid != 0) break; j = 512; }

        float ang = (-6.2831854820251465f * (float)j) * (1.0f / 1024.0f);
        float si = sinf(ang), co = cosf(ang);

        c32 onep { 1.0f + co,  si };
        c32 onem { 1.0f - co, -si };
        c32 invp = crecip(onep);
        c32 z    = cmul({ 2.0f*onem.x, 2.0f*onem.y }, invp);
        c32 z2   = cmul(z, z);

        c32 S00{0,0}, S01{0,0}, S10{0,0}, S11{0,0};
        #pragma unroll 8
        for (int n = 0; n < N_DIM; ++n) {
            float4 p0 = polA[n];
            float4 p1 = polB[n];
            float4 p2 = polC[n];
            // D = z^2 - 2*Re(wdt)*z + |wdt|^2   (shared denominator of pole pair)
            float Dx = fmaf(p0.x, z.x, z2.x) + p0.y;
            float Dy = fmaf(p0.x, z.y, z2.y);
            float s  = 1.0f / (Dx*Dx + Dy*Dy);
            float rx = Dx*s, ry = -Dy*s;

            // each v: numer = alpha*z - beta ; S += numer * rD
            {   float nx = fmaf(p0.z, z.x, -p0.w), ny = p0.z*z.y;
                S00.x += nx*rx - ny*ry; S00.y += nx*ry + ny*rx; }
            {   float nx = fmaf(p1.x, z.x, -p1.y), ny = p1.x*z.y;
                S01.x += nx*rx - ny*ry; S01.y += nx*ry + ny*rx; }
            {   float nx = fmaf(p1.z, z.x, -p1.w), ny = p1.z*z.y;
                S10.x += nx*rx - ny*ry; S10.y += nx*ry + ny*rx; }
            {   float nx = fmaf(p2.x, z.x, -p2.y), ny = p2.x*z.y;
                S11.x += nx*rx - ny*ry; S11.y += nx*ry + ny*rx; }
        }
        // r = dt * S
        c32 r00 { S00.x*dt, S00.y*dt };
        c32 r01 { S01.x*dt, S01.y*dt };
        c32 r10 { S10.x*dt, S10.y*dt };
        c32 r11 { S11.x*dt, S11.y*dt };

        c32 den { 1.0f + r11.x, r11.y };
        c32 corr = cmul(cmul(r01, r10), crecip(den));
        c32 kf { r00.x - corr.x, r00.y - corr.y };
        kf = cmul(kf, { 2.0f*invp.x, 2.0f*invp.y });

        Ksh[j] = make_float2(kf.x, kf.y);
    }
    __syncthreads();

    // ---------------- Phase C1: Hermitian -> complex packing ----------------
    // Y[j] = (K[j]+conj(K[M-j]))/2 + i*e^{+2pi i j/L} * (K[j]-conj(K[M-j]))/2
    {
        int j = tid;
        float2 Kj = Ksh[j];
        float2 Kr = Ksh[M_FFT - j];       // j=0 -> Ksh[512]
        float hsx = 0.5f*(Kj.x + Kr.x), hsy = 0.5f*(Kj.y - Kr.y);
        float hdx = 0.5f*(Kj.x - Kr.x), hdy = 0.5f*(Kj.y + Kr.y);
        float ang = 6.2831854820251465f * (float)j * (1.0f/1024.0f);
        float se = sinf(ang), ce = cosf(ang);
        // i*e = (-se, ce); t = (i*e) * hd
        float tx = -se*hdx - ce*hdy;
        float ty = -se*hdy + ce*hdx;
        Are[j] = hsx + tx;
        Aim[j] = hsy + ty;
    }
    __syncthreads();

    // ---------------- Phase C2: Stockham radix-2 IFFT (size 512) ----------------
    {
        float* sr = Are; float* si_ = Aim;
        float* dr = Bre; float* di = Bim;
        int m = 1;
        #pragma unroll
        for (int st = 0; st < 9; ++st) {
            if (tid < M_FFT/2) {
                int t  = tid;
                int jm = t & ~(m - 1);         // j*m
                float c0r = sr[t],        c0i = si_[t];
                float c1r = sr[t + 256],  c1i = si_[t + 256];
                float wr_ = twr[jm],      wi_ = twi[jm];
                int o0 = t + jm;               // k + 2*j*m
                int o1 = o0 + m;
                dr[o0] = c0r + c1r;
                di[o0] = c0i + c1i;
                float ur = c0r - c1r, ui = c0i - c1i;
                dr[o1] = ur*wr_ - ui*wi_;
                di[o1] = ur*wi_ + ui*wr_;
            }
            __syncthreads();
            float* tr = sr; sr = dr; dr = tr;
            float* ti = si_; si_ = di; di = ti;
            m <<= 1;
        }
        // result (natural order) now in sr/si_ ; x[2m]=Re y[m], x[2m+1]=Im y[m]
        const float scale = 1.0f / 512.0f;
        float2 o = make_float2(sr[tid]*scale, si_[tid]*scale);
        ((float2*)out)[h*(L_LEN/2) + tid] = o;
    }
}

extern "C" void kernel_launch(void* const* d_in, const int* in_sizes, int n_in,
                              void* d_out, int out_size, void* d_ws, size_t ws_size,
                              hipStream_t stream) {
    const float* log_dt     = (const float*)d_in[0];
    const float* inv_w_real = (const float*)d_in[1];
    const float* w_imag     = (const float*)d_in[2];
    const float* B_ri       = (const float*)d_in[3];
    const float* C_ri       = (const float*)d_in[4];
    const float* P_ri       = (const float*)d_in[5];
    // d_in[6] = L (constant 1024, baked in)

    ssk_nplr_kernel<<<H_DIM, 512, 0, stream>>>(log_dt, inv_w_real, w_imag,
                                               B_ri, C_ri, P_ri, (float*)d_out);
}

// Round 3
// 17.055 us; speedup vs baseline: 5.1845x; 1.3977x over previous
//
#include <hip/hip_runtime.h>
#include <math.h>

#define H_DIM 512
#define N_DIM 32
#define L_LEN 1024

// DIF radix-2 inverse FFT butterfly twiddle: W(s, r) = e^{+pi*i*r/s}
// Stage order s = 256 (fused with Hermitian packing), 128, 64 (LDS), 32..1 (shfl).
// Output lands bit-reversed: thread t holds y[bitrev9(t)].

__launch_bounds__(576, 5)
__global__ void ssk_nplr_kernel(const float* __restrict__ log_dt,
                                const float* __restrict__ inv_w_real,
                                const float* __restrict__ w_imag,
                                const float* __restrict__ B_ri,
                                const float* __restrict__ C_ri,
                                const float* __restrict__ P_ri,
                                float* __restrict__ out)
{
    __shared__ float2 Ksh[513];
    __shared__ float2 polD[N_DIM];   // {-2*Re(w*dt), |w*dt|^2}
    __shared__ float4 polA[N_DIM];   // a00,a01,a10,a11  (numer = a*z - b over shared denom)
    __shared__ float4 polB[N_DIM];   // b00,b01,b10,b11
    __shared__ float  Sre[512], Sim[512];
    __shared__ float  Tre[512], Tim[512];

    const int t = threadIdx.x;
    const int h = blockIdx.x;
    const float dt = expf(log_dt[h]);

    // ---------------- Phase A: per-h pole coefficients ----------------
    if (t < N_DIM) {
        const int n = t;
        float wr = -expf(inv_w_real[n]);   // S=1
        float wi = w_imag[n];
        float wdx = wr * dt, wdy = wi * dt;
        float Bx = B_ri[2*n],               By = B_ri[2*n+1];
        float Cx = C_ri[h*2*N_DIM + 2*n],   Cy = C_ri[h*2*N_DIM + 2*n+1];
        float Px = P_ri[2*n],               Py = P_ri[2*n+1];
        // v00=B*C, v01=B*conj(P), v10=P*C, v11=|P|^2 (real)
        float v00x = Bx*Cx - By*Cy, v00y = Bx*Cy + By*Cx;
        float v01x = Bx*Px + By*Py, v01y = By*Px - Bx*Py;
        float v10x = Px*Cx - Py*Cy, v10y = Px*Cy + Py*Cx;
        float v11x = Px*Px + Py*Py;
        polD[n] = make_float2(-2.0f*wdx, wdx*wdx + wdy*wdy);
        polA[n] = make_float4(2.0f*v00x, 2.0f*v01x, 2.0f*v10x, 2.0f*v11x);
        polB[n] = make_float4(2.0f*(v00x*wdx + v00y*wdy),
                              2.0f*(v01x*wdx + v01y*wdy),
                              2.0f*(v10x*wdx + v10y*wdy),
                              2.0f*(v11x*wdx));            // v11y = 0
    }
    __syncthreads();

    // ---------------- Phase B: k_f[j] ----------------
    // threads 0..511 -> j = t ; wave 8 (512..575) redundantly computes j = 512.
    const int j = (t < 512) ? t : 512;
    float ang = (-6.2831854820251465f * (float)j) * (1.0f/1024.0f);
    float si = sinf(ang), co = cosf(ang);          // omega = e^{-2pi i j/1024}

    float px = 1.0f + co, py = si;                 // 1 + omega
    float pinv = 1.0f / (px*px + py*py);
    float ipx = px*pinv, ipy = -py*pinv;           // 1/(1+omega)
    float mx = 1.0f - co, my = -si;                // 1 - omega
    float zx = 2.0f*(mx*ipx - my*ipy);             // z = 2(1-w)/(1+w)
    float zy = 2.0f*(mx*ipy + my*ipx);
    float z2x = zx*zx - zy*zy;
    float z2y = 2.0f*zx*zy;

    float U0x=0,U0y=0,U1x=0,U1y=0,U2x=0,U2y=0,U3x=0,U3y=0;
    float V0x=0,V0y=0,V1x=0,V1y=0,V2x=0,V2y=0,V3x=0,V3y=0;
    #pragma unroll 4
    for (int n = 0; n < N_DIM; ++n) {
        float2 d  = polD[n];
        float4 A  = polA[n];
        float4 Bv = polB[n];
        // shared pole-pair denominator D = z^2 - 2Re(wdt) z + |wdt|^2
        float Dx = fmaf(d.x, zx, z2x) + d.y;
        float Dy = fmaf(d.x, zy, z2y);
        float s  = __builtin_amdgcn_rcpf(fmaf(Dx, Dx, Dy*Dy));
        float rx = Dx*s, ry = -Dy*s;               // 1/D
        // S_v = z*U_v - V_v with U += a/D, V += b/D
        U0x = fmaf(A.x,  rx, U0x); U0y = fmaf(A.x,  ry, U0y);
        U1x = fmaf(A.y,  rx, U1x); U1y = fmaf(A.y,  ry, U1y);
        U2x = fmaf(A.z,  rx, U2x); U2y = fmaf(A.z,  ry, U2y);
        U3x = fmaf(A.w,  rx, U3x); U3y = fmaf(A.w,  ry, U3y);
        V0x = fmaf(Bv.x, rx, V0x); V0y = fmaf(Bv.x, ry, V0y);
        V1x = fmaf(Bv.y, rx, V1x); V1y = fmaf(Bv.y, ry, V1y);
        V2x = fmaf(Bv.z, rx, V2x); V2y = fmaf(Bv.z, ry, V2y);
        V3x = fmaf(Bv.w, rx, V3x); V3y = fmaf(Bv.w, ry, V3y);
    }
    // r = dt * (z*U - V)
    float r00x = dt*(zx*U0x - zy*U0y - V0x), r00y = dt*(zx*U0y + zy*U0x - V0y);
    float r01x = dt*(zx*U1x - zy*U1y - V1x), r01y = dt*(zx*U1y + zy*U1x - V1y);
    float r10x = dt*(zx*U2x - zy*U2y - V2x), r10y = dt*(zx*U2y + zy*U2x - V2y);
    float r11x = dt*(zx*U3x - zy*U3y - V3x), r11y = dt*(zx*U3y + zy*U3x - V3y);

    // k_f = (r00 - r01*r10/(1+r11)) * 2/(1+omega)
    float dnx = 1.0f + r11x, dny = r11y;
    float dinv = 1.0f / (dnx*dnx + dny*dny);
    float idx_ = dnx*dinv, idy = -dny*dinv;
    float m01x = r01x*r10x - r01y*r10y;
    float m01y = r01x*r10y + r01y*r10x;
    float cxx = m01x*idx_ - m01y*idy;
    float cyy = m01x*idy + m01y*idx_;
    float kfx = r00x - cxx, kfy = r00y - cyy;
    float fxv = 2.0f*(kfx*ipx - kfy*ipy);
    float fyv = 2.0f*(kfx*ipy + kfy*ipx);
    if (t <= 512) Ksh[j] = make_float2(fxv, fyv);
    __syncthreads();

    // ---------------- Phase C: irfft via packed complex IFFT(512), DIF ----------------
    float xr = 0.0f, xi = 0.0f;
    if (t < 512) {
        // Hermitian -> complex packing, fused with s=256 butterfly (in registers).
        // Y[q] = hs(q) + i*e^{+2pi i q/1024} * hd(q)
        float2 Ka = Ksh[t];
        float2 Kb = Ksh[512 - t];
        const int tb = t ^ 256;
        float2 Kc = Ksh[tb];
        float2 Kd = Ksh[512 - tb];
        float Wx = co, Wy = -si;                   // e^{+2pi i t/1024} (reuse Phase B sincos)
        float hsx = 0.5f*(Ka.x + Kb.x), hsy = 0.5f*(Ka.y - Kb.y);
        float hdx = 0.5f*(Ka.x - Kb.x), hdy = 0.5f*(Ka.y + Kb.y);
        float Yax = hsx - Wy*hdx - Wx*hdy;
        float Yay = hsy - Wy*hdy + Wx*hdx;
        // partner twiddle: e^{+2pi i (t^256)/1024} = (t<256 ? i : -i) * W
        float Wbx = (t < 256) ? -Wy :  Wy;
        float Wby = (t < 256) ?  Wx : -Wx;
        float hsx2 = 0.5f*(Kc.x + Kd.x), hsy2 = 0.5f*(Kc.y - Kd.y);
        float hdx2 = 0.5f*(Kc.x - Kd.x), hdy2 = 0.5f*(Kc.y + Kd.y);
        float Ybx = hsx2 - Wby*hdx2 - Wbx*hdy2;
        float Yby = hsy2 - Wby*hdy2 + Wbx*hdx2;
        // s = 256 butterfly
        if (t & 256) {
            float dr = Ybx - Yax, di = Yby - Yay;
            float aw = 3.14159265358979f * (float)(t & 255) * (1.0f/256.0f);
            float ws, wc; __sincosf(aw, &ws, &wc);
            xr = dr*wc - di*ws; xi = dr*ws + di*wc;
        } else {
            xr = Yax + Ybx; xi = Yay + Yby;
        }
        Sre[t] = xr; Sim[t] = xi;
    }
    __syncthreads();

    if (t < 512) {
        // s = 128 (LDS exchange)
        float pr = Sre[t ^ 128], pi_ = Sim[t ^ 128];
        if (t & 128) {
            float dr = pr - xr, di = pi_ - xi;
            float aw = 3.14159265358979f * (float)(t & 127) * (1.0f/128.0f);
            float ws, wc; __sincosf(aw, &ws, &wc);
            xr = dr*wc - di*ws; xi = dr*ws + di*wc;
        } else { xr += pr; xi += pi_; }
        Tre[t] = xr; Tim[t] = xi;
    }
    __syncthreads();

    if (t < 512) {
        // s = 64 (LDS exchange)
        float pr = Tre[t ^ 64], pi_ = Tim[t ^ 64];
        if (t & 64) {
            float dr = pr - xr, di = pi_ - xi;
            float aw = 3.14159265358979f * (float)(t & 63) * (1.0f/64.0f);
            float ws, wc; __sincosf(aw, &ws, &wc);
            xr = dr*wc - di*ws; xi = dr*ws + di*wc;
        } else { xr += pr; xi += pi_; }

        // s = 32..2 (wave-internal shfl butterflies, no barriers)
        #define FFT_STAGE(S_) {                                             \
            float pr2 = __shfl_xor(xr, S_), pi2 = __shfl_xor(xi, S_);       \
            if (t & S_) {                                                   \
                float dr = pr2 - xr, di = pi2 - xi;                         \
                float aw = 3.14159265358979f * (float)(t & (S_-1)) * (1.0f/(float)S_); \
                float ws, wc; __sincosf(aw, &ws, &wc);                      \
                xr = dr*wc - di*ws; xi = dr*ws + di*wc;                     \
            } else { xr += pr2; xi += pi2; }                                \
        }
        FFT_STAGE(32)
        FFT_STAGE(16)
        FFT_STAGE(8)
        FFT_STAGE(4)
        FFT_STAGE(2)
        #undef FFT_STAGE
        // s = 1 (twiddle = 1)
        {
            float pr2 = __shfl_xor(xr, 1), pi2 = __shfl_xor(xi, 1);
            if (t & 1) { xr = pr2 - xr; xi = pi2 - xi; }
            else       { xr += pr2; xi += pi2; }
        }
        // thread t holds y[bitrev9(t)]; y[m] packs time samples (x[2m], x[2m+1])
        unsigned m = __brev((unsigned)t) >> 23;
        ((float2*)out)[h*512 + m] = make_float2(xr*(1.0f/512.0f), xi*(1.0f/512.0f));
    }
}

extern "C" void kernel_launch(void* const* d_in, const int* in_sizes, int n_in,
                              void* d_out, int out_size, void* d_ws, size_t ws_size,
                              hipStream_t stream) {
    const float* log_dt     = (const float*)d_in[0];
    const float* inv_w_real = (const float*)d_in[1];
    const float* w_imag     = (const float*)d_in[2];
    const float* B_ri       = (const float*)d_in[3];
    const float* C_ri       = (const float*)d_in[4];
    const float* P_ri       = (const float*)d_in[5];
    // d_in[6] = L (constant 1024, baked in)

    ssk_nplr_kernel<<<H_DIM, 576, 0, stream>>>(log_dt, inv_w_real, w_imag,
                                               B_ri, C_ri, P_ri, (float*)d_out);
}

// Round 5
// 15.737 us; speedup vs baseline: 5.6185x; 1.0837x over previous
//
#include <hip/hip_runtime.h>
#include <math.h>

#define H_DIM 512
#define N_DIM 32
#define L_LEN 1024

typedef float v2f __attribute__((ext_vector_type(2)));
__device__ __forceinline__ v2f splat2(float a) { return (v2f){a, a}; }

// DIF radix-2 inverse FFT; butterfly twiddle W(s, r) = e^{+pi*i*r/s}.
// Stages: s=256 fused with Hermitian packing, 128/64 via LDS, 32..1 via shfl.
// Thread t ends holding y[bitrev9(t)].

__launch_bounds__(576, 7)
__global__ void ssk_nplr_kernel(const float* __restrict__ log_dt,
                                const float* __restrict__ inv_w_real,
                                const float* __restrict__ w_imag,
                                const float* __restrict__ B_ri,
                                const float* __restrict__ C_ri,
                                const float* __restrict__ P_ri,
                                float* __restrict__ out)
{
    __shared__ float2 Ksh[513];
    __shared__ float2 polD[N_DIM];   // {-2*Re(w*dt), |w*dt|^2}
    __shared__ float4 polA[N_DIM];   // a00,a01,a10,a11  (numer = a*z - b)
    __shared__ float4 polB[N_DIM];   // b00,b01,b10,b11
    __shared__ float  Sre[512], Sim[512];
    __shared__ float  Tre[512], Tim[512];

    const int t = threadIdx.x;
    const int h = blockIdx.x;
    const float dt = expf(log_dt[h]);

    // ---------------- Phase A: per-h pole coefficients ----------------
    if (t < N_DIM) {
        const int n = t;
        float wr = -expf(inv_w_real[n]);   // S=1
        float wi = w_imag[n];
        float wdx = wr * dt, wdy = wi * dt;
        float Bx = B_ri[2*n],               By = B_ri[2*n+1];
        float Cx = C_ri[h*2*N_DIM + 2*n],   Cy = C_ri[h*2*N_DIM + 2*n+1];
        float Px = P_ri[2*n],               Py = P_ri[2*n+1];
        float v00x = Bx*Cx - By*Cy, v00y = Bx*Cy + By*Cx;   // B*C
        float v01x = Bx*Px + By*Py, v01y = By*Px - Bx*Py;   // B*conj(P)
        float v10x = Px*Cx - Py*Cy, v10y = Px*Cy + Py*Cx;   // P*C
        float v11x = Px*Px + Py*Py;                         // |P|^2
        polD[n] = make_float2(-2.0f*wdx, wdx*wdx + wdy*wdy);
        polA[n] = make_float4(2.0f*v00x, 2.0f*v01x, 2.0f*v10x, 2.0f*v11x);
        polB[n] = make_float4(2.0f*(v00x*wdx + v00y*wdy),
                              2.0f*(v01x*wdx + v01y*wdy),
                              2.0f*(v10x*wdx + v10y*wdy),
                              2.0f*(v11x*wdx));             // v11y = 0
    }
    __syncthreads();

    // ---------------- Phase B: k_f[j] ----------------
    // threads 0..511 -> j = t ; wave 8 redundantly computes j = 512.
    const int j = (t < 512) ? t : 512;
    // omega = e^{-2pi i j/1024}; hw sin/cos take REVOLUTIONS (exact dyadic input).
    // j=512: rev=-0.5 exactly -> hw gives (si=0, co=-1) -> 1/(1+omega) = inf/NaN.
    // The numpy reference computes sinf(-pi_f32) ~= +8.7422777e-8 (pi_f32 != pi),
    // giving a huge-but-finite z whose magnitude cancels to first order in k_f.
    // Emulate that path with the libm f32 constants (wave-uniform branch).
    float si, co;
    if (j == 512) {
        si = 8.7422777e-8f;
        co = -1.0f;
    } else {
        float rev = (float)j * (-0.0009765625f);           // -j/1024 revolutions
        si = __builtin_amdgcn_sinf(rev);
        co = __builtin_amdgcn_cosf(rev);
    }

    float px = 1.0f + co, py = si;                         // 1 + omega
    float pinv = 1.0f / (px*px + py*py);
    float ipx = px*pinv, ipy = -py*pinv;                   // 1/(1+omega)
    float mx = 1.0f - co, my = -si;                        // 1 - omega
    float zx = 2.0f*(mx*ipx - my*ipy);                     // z = 2(1-w)/(1+w)
    float zy = 2.0f*(mx*ipy + my*ipx);

    v2f Z  = { zx, zy };
    v2f Z2 = { zx*zx - zy*zy, 2.0f*zx*zy };

    v2f U0{0,0}, U1{0,0}, U2{0,0}, U3{0,0};
    v2f V0{0,0}, V1{0,0}, V2{0,0}, V3{0,0};
    #pragma unroll 4
    for (int n = 0; n < N_DIM; ++n) {
        float2 d  = polD[n];
        float4 A  = polA[n];
        float4 Bv = polB[n];
        // shared pole-pair denominator D = z^2 - 2Re(wdt) z + |wdt|^2
        v2f D = __builtin_elementwise_fma(splat2(d.x), Z, Z2);
        D.x += d.y;
        float s  = __builtin_amdgcn_rcpf(fmaf(D.x, D.x, D.y*D.y));
        v2f R = { D.x * s, -(D.y * s) };                   // 1/D
        // S_v = z*U_v - V_v with U += a/D, V += b/D   (packed fma pairs)
        U0 = __builtin_elementwise_fma(splat2(A.x),  R, U0);
        U1 = __builtin_elementwise_fma(splat2(A.y),  R, U1);
        U2 = __builtin_elementwise_fma(splat2(A.z),  R, U2);
        U3 = __builtin_elementwise_fma(splat2(A.w),  R, U3);
        V0 = __builtin_elementwise_fma(splat2(Bv.x), R, V0);
        V1 = __builtin_elementwise_fma(splat2(Bv.y), R, V1);
        V2 = __builtin_elementwise_fma(splat2(Bv.z), R, V2);
        V3 = __builtin_elementwise_fma(splat2(Bv.w), R, V3);
    }
    // r = dt * (z*U - V)
    float r00x = dt*(zx*U0.x - zy*U0.y - V0.x), r00y = dt*(zx*U0.y + zy*U0.x - V0.y);
    float r01x = dt*(zx*U1.x - zy*U1.y - V1.x), r01y = dt*(zx*U1.y + zy*U1.x - V1.y);
    float r10x = dt*(zx*U2.x - zy*U2.y - V2.x), r10y = dt*(zx*U2.y + zy*U2.x - V2.y);
    float r11x = dt*(zx*U3.x - zy*U3.y - V3.x), r11y = dt*(zx*U3.y + zy*U3.x - V3.y);

    // k_f = (r00 - r01*r10/(1+r11)) * 2/(1+omega)
    float dnx = 1.0f + r11x, dny = r11y;
    float dinv = 1.0f / (dnx*dnx + dny*dny);
    float idx_ = dnx*dinv, idy = -dny*dinv;
    float m01x = r01x*r10x - r01y*r10y;
    float m01y = r01x*r10y + r01y*r10x;
    float kfx = r00x - (m01x*idx_ - m01y*idy);
    float kfy = r00y - (m01x*idy + m01y*idx_);
    float fxv = 2.0f*(kfx*ipx - kfy*ipy);
    float fyv = 2.0f*(kfx*ipy + kfy*ipx);
    if (t <= 512) Ksh[j] = make_float2(fxv, fyv);
    __syncthreads();

    // ---------------- Phase C: irfft via packed complex IFFT(512), DIF ----------------
    float xr = 0.0f, xi = 0.0f;
    if (t < 512) {
        // Hermitian -> complex packing fused with the s=256 butterfly.
        float2 Ka = Ksh[t];
        float2 Kb = Ksh[512 - t];
        const int tb = t ^ 256;
        float2 Kc = Ksh[tb];
        float2 Kd = Ksh[512 - tb];
        float Wx = co, Wy = -si;                   // e^{+2pi i t/1024}
        float hsx = 0.5f*(Ka.x + Kb.x), hsy = 0.5f*(Ka.y - Kb.y);
        float hdx = 0.5f*(Ka.x - Kb.x), hdy = 0.5f*(Ka.y + Kb.y);
        float Yax = hsx - Wy*hdx - Wx*hdy;
        float Yay = hsy - Wy*hdy + Wx*hdx;
        // partner twiddle: e^{+2pi i (t^256)/1024} = (t<256 ? i : -i) * W
        float Wbx = (t < 256) ? -Wy :  Wy;
        float Wby = (t < 256) ?  Wx : -Wx;
        float hsx2 = 0.5f*(Kc.x + Kd.x), hsy2 = 0.5f*(Kc.y - Kd.y);
        float hdx2 = 0.5f*(Kc.x - Kd.x), hdy2 = 0.5f*(Kc.y + Kd.y);
        float Ybx = hsx2 - Wby*hdx2 - Wbx*hdy2;
        float Yby = hsy2 - Wby*hdy2 + Wbx*hdx2;
        if (t & 256) {
            float dr = Ybx - Yax, di = Yby - Yay;
            float wrev = (float)(t & 255) * (1.0f/512.0f);   // revolutions
            float ws = __builtin_amdgcn_sinf(wrev);
            float wc = __builtin_amdgcn_cosf(wrev);
            xr = dr*wc - di*ws; xi = dr*ws + di*wc;
        } else {
            xr = Yax + Ybx; xi = Yay + Yby;
        }
        Sre[t] = xr; Sim[t] = xi;
    }
    __syncthreads();

    if (t < 512) {
        // s = 128 (LDS exchange)
        float pr = Sre[t ^ 128], pi_ = Sim[t ^ 128];
        if (t & 128) {
            float dr = pr - xr, di = pi_ - xi;
            float wrev = (float)(t & 127) * (1.0f/256.0f);
            float ws = __builtin_amdgcn_sinf(wrev);
            float wc = __builtin_amdgcn_cosf(wrev);
            xr = dr*wc - di*ws; xi = dr*ws + di*wc;
        } else { xr += pr; xi += pi_; }
        Tre[t] = xr; Tim[t] = xi;
    }
    __syncthreads();

    if (t < 512) {
        // s = 64 (LDS exchange)
        float pr = Tre[t ^ 64], pi_ = Tim[t ^ 64];
        if (t & 64) {
            float dr = pr - xr, di = pi_ - xi;
            float wrev = (float)(t & 63) * (1.0f/128.0f);
            float ws = __builtin_amdgcn_sinf(wrev);
            float wc = __builtin_amdgcn_cosf(wrev);
            xr = dr*wc - di*ws; xi = dr*ws + di*wc;
        } else { xr += pr; xi += pi_; }

        // s = 32..2 (wave-internal shfl butterflies)
        #define FFT_STAGE(S_) {                                             \
            float pr2 = __shfl_xor(xr, S_), pi2 = __shfl_xor(xi, S_);       \
            if (t & S_) {                                                   \
                float dr = pr2 - xr, di = pi2 - xi;                         \
                float wrev = (float)(t & (S_-1)) * (0.5f/(float)S_);        \
                float ws = __builtin_amdgcn_sinf(wrev);                     \
                float wc = __builtin_amdgcn_cosf(wrev);                     \
                xr = dr*wc - di*ws; xi = dr*ws + di*wc;                     \
            } else { xr += pr2; xi += pi2; }                                \
        }
        FFT_STAGE(32)
        FFT_STAGE(16)
        FFT_STAGE(8)
        FFT_STAGE(4)
        FFT_STAGE(2)
        #undef FFT_STAGE
        // s = 1 (twiddle = 1)
        {
            float pr2 = __shfl_xor(xr, 1), pi2 = __shfl_xor(xi, 1);
            if (t & 1) { xr = pr2 - xr; xi = pi2 - xi; }
            else       { xr += pr2; xi += pi2; }
        }
        // thread t holds y[bitrev9(t)]; y[m] packs (x[2m], x[2m+1])
        unsigned m = __brev((unsigned)t) >> 23;
        ((float2*)out)[h*512 + m] = make_float2(xr*(1.0f/512.0f), xi*(1.0f/512.0f));
    }
}

extern "C" void kernel_launch(void* const* d_in, const int* in_sizes, int n_in,
                              void* d_out, int out_size, void* d_ws, size_t ws_size,
                              hipStream_t stream) {
    const float* log_dt     = (const float*)d_in[0];
    const float* inv_w_real = (const float*)d_in[1];
    const float* w_imag     = (const float*)d_in[2];
    const float* B_ri       = (const float*)d_in[3];
    const float* C_ri       = (const float*)d_in[4];
    const float* P_ri       = (const float*)d_in[5];
    // d_in[6] = L (constant 1024, baked in)

    ssk_nplr_kernel<<<H_DIM, 576, 0, stream>>>(log_dt, inv_w_real, w_imag,
                                               B_ri, C_ri, P_ri, (float*)d_out);
}